// Round 13
// baseline (22.993 us; speedup 1.0000x reference)
//
#include <hip/hip_runtime.h>

// B=128, x1/x2/x3 (B,2048,7,7) f32, W (14,2048), b (14,)
// softmax over singleton axis == 1.0 exactly  =>  h = 2*x1 + x2  (x3 unused!)
// feats[b,n] = mean_c(2*x1 + x2) ; logits = feats @ W^T + b
// Output layout: logits (128*14) then feats (128*2048), f32 flat.
//
// Round-13: 3-deep register prefetch on the wave-autonomous r12 structure.
// BDP arithmetic: 24.6 GB/s/CU x ~375ns = 9.2 KB must be in flight per CU;
// 2-deep staging held only ~6 KB. Main loads issued 2 subtiles ahead
// (sets s%3), tail 1 ahead (sets s%2): ~88 staging VGPRs, <=128 total ->
// 16 waves/CU kept. Single wave-private LDS buffer (DS pipe is in-order
// per wave; write-after-read can't bypass) = 13.5 KB/block. No barriers in
// the data loop (r12); gather kernel kept (r11: memset+atomics cost more).

#define FC_B 128
#define FC_N 2048
#define FC_J 14
#define SUBT 4                       // subtiles per wave
#define SUB_ROWS 16
#define SUB_F (SUB_ROWS * 49)        // 784 floats
#define SUB_V (SUB_F / 4)            // 196 float4
#define WCHUNK_V (SUBT * SUB_V)      // 784 float4 per wave
#define RPB 256                      // rows per block (4 waves * 64)
#define NBLK (FC_B * FC_N / RPB)     // 1024 blocks = 4/CU
#define BPB (FC_N / RPB)             // 8 blocks per batch row

__global__ __launch_bounds__(256) void fused_kernel(
    const float* __restrict__ x1, const float* __restrict__ x2,
    const float* __restrict__ W,
    float* __restrict__ feats, float* __restrict__ part)
{
    const int tid = threadIdx.x;
    const int w = tid >> 6;          // wave 0..3
    const int lane = tid & 63;
    __shared__ float buf[4][SUB_F];                  // 12.5 KB, wave-private
    __shared__ __align__(16) float sf[RPB];          // 1 KB

    const float4* q1 = (const float4*)x1
                     + (size_t)blockIdx.x * (RPB * 49 / 4) + w * WCHUNK_V;
    const float4* q2 = (const float4*)x2
                     + (size_t)blockIdx.x * (RPB * 49 / 4) + w * WCHUNK_V;

    // 3-deep main staging (sets s%3), 2-deep tail staging (sets s%2)
    float4 a0[3], a1[3], a2[3], c0[3], c1[3], c2[3];
    float4 at[2], ct[2];

    // prologue: subtiles 0 and 1
    {
        const float4 *Q1 = q1, *Q2 = q2;
        a0[0] = Q1[lane]; a1[0] = Q1[lane + 64]; a2[0] = Q1[lane + 128];
        c0[0] = Q2[lane]; c1[0] = Q2[lane + 64]; c2[0] = Q2[lane + 128];
        if (lane < 4) { at[0] = Q1[192 + lane]; ct[0] = Q2[192 + lane]; }
    }
    {
        const float4 *Q1 = q1 + SUB_V, *Q2 = q2 + SUB_V;
        a0[1] = Q1[lane]; a1[1] = Q1[lane + 64]; a2[1] = Q1[lane + 128];
        c0[1] = Q2[lane]; c1[1] = Q2[lane + 64]; c2[1] = Q2[lane + 128];
        if (lane < 4) { at[1] = Q1[192 + lane]; ct[1] = Q2[192 + lane]; }
    }

    const int r = lane >> 2;         // row within subtile 0..15
    const int t4 = lane & 3;

    #pragma unroll
    for (int s = 0; s < SUBT; ++s) {
        const int cm = s % 3;        // main set (compile-time under unroll)
        const int ct2 = s & 1;       // tail set

        // issue main loads 2 subtiles ahead
        if (s + 2 < SUBT) {
            const int nm = (s + 2) % 3;
            const float4* Q1 = q1 + (s + 2) * SUB_V;
            const float4* Q2 = q2 + (s + 2) * SUB_V;
            a0[nm] = Q1[lane]; a1[nm] = Q1[lane + 64]; a2[nm] = Q1[lane + 128];
            c0[nm] = Q2[lane]; c1[nm] = Q2[lane + 64]; c2[nm] = Q2[lane + 128];
        }
        // issue tail loads 1 subtile ahead
        if (s + 1 < SUBT && lane < 4) {
            const float4* Q1 = q1 + (s + 1) * SUB_V;
            const float4* Q2 = q2 + (s + 1) * SUB_V;
            at[ct2 ^ 1] = Q1[192 + lane];
            ct[ct2 ^ 1] = Q2[192 + lane];
        }

        // combine 2*x1+x2 -> wave-private LDS (single buffer: DS in-order
        // per wave makes write-after-read safe without double buffering)
        float4* smv = (float4*)buf[w];
        float4 w0, w1, w2;
        w0.x = 2.f*a0[cm].x + c0[cm].x; w0.y = 2.f*a0[cm].y + c0[cm].y;
        w0.z = 2.f*a0[cm].z + c0[cm].z; w0.w = 2.f*a0[cm].w + c0[cm].w;
        w1.x = 2.f*a1[cm].x + c1[cm].x; w1.y = 2.f*a1[cm].y + c1[cm].y;
        w1.z = 2.f*a1[cm].z + c1[cm].z; w1.w = 2.f*a1[cm].w + c1[cm].w;
        w2.x = 2.f*a2[cm].x + c2[cm].x; w2.y = 2.f*a2[cm].y + c2[cm].y;
        w2.z = 2.f*a2[cm].z + c2[cm].z; w2.w = 2.f*a2[cm].w + c2[cm].w;
        smv[lane] = w0; smv[lane + 64] = w1; smv[lane + 128] = w2;
        if (lane < 4) {
            float4 wt;
            wt.x = 2.f*at[ct2].x + ct[ct2].x; wt.y = 2.f*at[ct2].y + ct[ct2].y;
            wt.z = 2.f*at[ct2].z + ct[ct2].z; wt.w = 2.f*at[ct2].w + ct[ct2].w;
            smv[192 + lane] = wt;
        }

        // wave-local ordering only
        asm volatile("s_waitcnt lgkmcnt(0)" ::: "memory");

        // 4-lane/row reduce; banks = (17r+t) mod 32 = 2 lanes/bank (free)
        const float* rp = buf[w] + r * 49;
        float v = 0.f;
        #pragma unroll
        for (int k = 0; k < 12; ++k)
            v += rp[t4 + 4 * k];
        if (t4 == 0) v += rp[48];
        v += __shfl_xor(v, 1, 4);
        v += __shfl_xor(v, 2, 4);
        if (t4 == 0) sf[w * 64 + s * SUB_ROWS + r] = v * (1.0f / 49.0f);
    }

    // per-wave coalesced feats write (wave's own 64 rows = 16 float4)
    asm volatile("s_waitcnt lgkmcnt(0)" ::: "memory");
    if (lane < 16)
        ((float4*)(feats + (size_t)blockIdx.x * RPB + w * 64))[lane] =
            ((const float4*)(sf + w * 64))[lane];

    __syncthreads();   // sf complete across all 4 waves

    // ---- fc partials: 224 threads, 16-lane segmented dot ----
    if (tid < 224) {
        const int j = tid >> 4;              // 0..13
        const int s16 = tid & 15;
        const int bb = blockIdx.x >> 3;      // batch index (8 blocks/batch)
        const int blkin = blockIdx.x & (BPB - 1);
        const float* wrow = W + j * FC_N + blkin * RPB;   // W is L2-resident
        float acc = 0.f;
        #pragma unroll
        for (int k = 0; k < 16; ++k)
            acc += sf[s16 + 16 * k] * wrow[s16 + 16 * k];
        acc += __shfl_xor(acc, 1, 16);
        acc += __shfl_xor(acc, 2, 16);
        acc += __shfl_xor(acc, 4, 16);
        acc += __shfl_xor(acc, 8, 16);
        if (s16 == 0)
            part[((bb * FC_J + j) << 3) + blkin] = acc;   // part[b][j][blkin]
    }
}

__global__ __launch_bounds__(256) void gather_kernel(const float* __restrict__ part,
                                                     const float* __restrict__ bias,
                                                     float* __restrict__ logits) {
    const int idx = blockIdx.x * 256 + threadIdx.x;
    if (idx >= FC_B * FC_J) return;
    const float4 p0 = ((const float4*)(part + ((size_t)idx << 3)))[0];
    const float4 p1 = ((const float4*)(part + ((size_t)idx << 3)))[1];
    logits[idx] = p0.x + p0.y + p0.z + p0.w
                + p1.x + p1.y + p1.z + p1.w + bias[idx % FC_J];
}

extern "C" void kernel_launch(void* const* d_in, const int* in_sizes, int n_in,
                              void* d_out, int out_size, void* d_ws, size_t ws_size,
                              hipStream_t stream) {
    const float* x1 = (const float*)d_in[0];
    const float* x2 = (const float*)d_in[1];
    // d_in[2] = x3 — provably unused (softmax over singleton axis == 1)
    const float* W = (const float*)d_in[3];
    const float* bias = (const float*)d_in[4];

    float* out = (float*)d_out;
    float* logits = out;                 // 128*14
    float* feats = out + FC_B * FC_J;    // 128*2048

    float* part = (float*)d_ws;          // 128*14*8*4 = 57 KB scratch

    fused_kernel<<<NBLK, 256, 0, stream>>>(x1, x2, W, feats, part);
    gather_kernel<<<(FC_B * FC_J + 255) / 256, 256, 0, stream>>>(part, bias, logits);
}